// Round 1
// baseline (87.524 us; speedup 1.0000x reference)
//
#include <hip/hip_runtime.h>
#include <hip/hip_bf16.h>

typedef short bf16x8 __attribute__((ext_vector_type(8)));
typedef float f32x4 __attribute__((ext_vector_type(4)));
typedef unsigned short u16;

#define B 128
#define LQ 32
#define LK 128
#define D 128

// ---------------------------------------------------------------------------
// ws layout:
//   l_bf16: B*LQ*D bf16 = 1 MiB        (offset 0)
//   r_bf16: B*LK*D bf16 = 4 MiB        (offset 1 MiB)
//   sims:   B*B   f32   = 64 KiB       (offset 5 MiB)
// ---------------------------------------------------------------------------

static __device__ inline u16 f2bf_rne(float f) {
  union { float f; unsigned u; } v; v.f = f;
  unsigned r = v.u + 0x7fffu + ((v.u >> 16) & 1u);  // round-to-nearest-even
  return (u16)(r >> 16);
}

// One wave per row (D=128 -> 2 floats/lane). Normalize + cast to bf16.
__global__ __launch_bounds__(256) void normalize_kernel(
    const float* __restrict__ left, const float* __restrict__ right,
    u16* __restrict__ l_out, u16* __restrict__ r_out) {
  int wave = (blockIdx.x * blockDim.x + threadIdx.x) >> 6;
  int lane = threadIdx.x & 63;
  const int n_l = B * LQ;
  const float* src; u16* dst; int row;
  if (wave < n_l) { src = left;  dst = l_out; row = wave; }
  else            { src = right; dst = r_out; row = wave - n_l; }
  float2 v = *reinterpret_cast<const float2*>(src + (size_t)row * D + lane * 2);
  float ss = v.x * v.x + v.y * v.y;
#pragma unroll
  for (int off = 1; off < 64; off <<= 1) ss += __shfl_xor(ss, off);
  float inv = 1.0f / fmaxf(sqrtf(ss), 1e-12f);
  u16 b0 = f2bf_rne(v.x * inv);
  u16 b1 = f2bf_rne(v.y * inv);
  unsigned packed = (unsigned)b0 | ((unsigned)b1 << 16);
  *reinterpret_cast<unsigned*>(dst + (size_t)row * D + lane * 2) = packed;
}

// Pair-sims: per (x,y), T[j][i] = sum_k r[y][j][k] * l[x][i][k]  (M=j=128,
// N=i=32, K=128 via 16x16x32 bf16 MFMA). Then sim[x][y] = sum_i max_j T.
// Grid: 512 blocks = 32 x-groups x 16 y-groups; 4 waves/block, wave = one x,
// 8 y per block. A/B fragments are contiguous-16B loads from row-major bf16.
__global__ __launch_bounds__(256) void maxsim_kernel(
    const u16* __restrict__ lb, const u16* __restrict__ rb,
    float* __restrict__ sims) {
  const int lane = threadIdx.x & 63;
  const int wv   = threadIdx.x >> 6;      // 0..3
  const int xg   = blockIdx.x >> 4;       // 0..31
  const int yg   = blockIdx.x & 15;       // 0..15
  const int x    = xg * 4 + wv;
  const int lo4  = lane & 15, hi2 = lane >> 4;
  const int frag_off = lo4 * D + hi2 * 8; // element offset within a 16-row tile

  // B operand (l[x]) fragments: fixed for whole block loop. B[k][i]=l[x][i][k].
  bf16x8 bfr[2][4];
#pragma unroll
  for (int ni = 0; ni < 2; ++ni)
#pragma unroll
    for (int k = 0; k < 4; ++k)
      bfr[ni][k] = *reinterpret_cast<const bf16x8*>(
          lb + (size_t)(x * LQ + ni * 16) * D + k * 32 + frag_off);

  for (int yy = 0; yy < 8; ++yy) {
    const int y = yg * 8 + yy;
    const u16* rbase = rb + (size_t)y * LK * D;
    f32x4 acc[8][2];
#pragma unroll
    for (int mj = 0; mj < 8; ++mj)
#pragma unroll
      for (int ni = 0; ni < 2; ++ni)
        acc[mj][ni] = f32x4{0.f, 0.f, 0.f, 0.f};

#pragma unroll
    for (int mj = 0; mj < 8; ++mj) {
      bf16x8 afr[4];
#pragma unroll
      for (int k = 0; k < 4; ++k)
        afr[k] = *reinterpret_cast<const bf16x8*>(
            rbase + (size_t)mj * 16 * D + k * 32 + frag_off);
#pragma unroll
      for (int k = 0; k < 4; ++k)
#pragma unroll
        for (int ni = 0; ni < 2; ++ni)
          acc[mj][ni] = __builtin_amdgcn_mfma_f32_16x16x32_bf16(
              afr[k], bfr[ni][k], acc[mj][ni], 0, 0, 0);
    }

    // Epilogue: lane holds T[mj*16 + hi2*4 + r][ni*16 + lo4].
    // max over j  = max over (mj, r) in-lane, then lanes xor 16/32.
    float cmax0 = -3.0e38f, cmax1 = -3.0e38f;
#pragma unroll
    for (int mj = 0; mj < 8; ++mj)
#pragma unroll
      for (int r = 0; r < 4; ++r) {
        cmax0 = fmaxf(cmax0, acc[mj][0][r]);
        cmax1 = fmaxf(cmax1, acc[mj][1][r]);
      }
    cmax0 = fmaxf(cmax0, __shfl_xor(cmax0, 16));
    cmax0 = fmaxf(cmax0, __shfl_xor(cmax0, 32));
    cmax1 = fmaxf(cmax1, __shfl_xor(cmax1, 16));
    cmax1 = fmaxf(cmax1, __shfl_xor(cmax1, 32));
    // sum over i: each lane now holds colmax(i=lo4) and colmax(i=16+lo4),
    // replicated across hi2. Butterfly over low 4 lane bits sums 16 cols.
    float s = cmax0 + cmax1;
#pragma unroll
    for (int off = 1; off <= 8; off <<= 1) s += __shfl_xor(s, off);
    if (lane == 0) sims[x * B + y] = s;
  }
}

// log-softmax + CE over the 128x128 sims matrix. One block, 128 threads.
__global__ void loss_kernel(const float* __restrict__ sims,
                            const float* __restrict__ logit_scale,
                            const int* __restrict__ pos_idx,
                            float* __restrict__ out) {
  __shared__ float red[B];
  int x = threadIdx.x;  // 0..127
  float scale = expf(logit_scale[0]);
  const float* row = sims + x * B;
  float m = -3.0e38f;
  for (int y = 0; y < B; ++y) m = fmaxf(m, row[y]);
  float ml = scale * m;
  float sum = 0.f;
  for (int y = 0; y < B; ++y) sum += expf(scale * row[y] - ml);
  int pos = pos_idx[x];
  float lp = scale * row[pos] - ml - logf(sum);
  red[x] = -lp;
  __syncthreads();
  if (x == 0) {
    float t = 0.f;
    for (int i = 0; i < B; ++i) t += red[i];
    out[0] = t / (float)B;
  }
}

extern "C" void kernel_launch(void* const* d_in, const int* in_sizes, int n_in,
                              void* d_out, int out_size, void* d_ws, size_t ws_size,
                              hipStream_t stream) {
  const float* left  = (const float*)d_in[0];
  const float* right = (const float*)d_in[1];
  const float* ls    = (const float*)d_in[2];
  const int*   pos   = (const int*)d_in[3];
  float* out = (float*)d_out;

  char* ws = (char*)d_ws;
  u16* lb   = (u16*)ws;                                        // 1 MiB
  u16* rbuf = (u16*)(ws + (size_t)B * LQ * D * 2);             // 4 MiB
  float* sims = (float*)(ws + (size_t)B * LQ * D * 2 + (size_t)B * LK * D * 2);

  int waves = B * LQ + B * LK;          // 20480 rows, 1 wave each
  normalize_kernel<<<waves / 4, 256, 0, stream>>>(left, right, lb, rbuf);
  maxsim_kernel<<<512, 256, 0, stream>>>(lb, rbuf, sims);
  loss_kernel<<<1, B, 0, stream>>>(sims, ls, pos, out);
}

// Round 2
// 83.067 us; speedup vs baseline: 1.0537x; 1.0537x over previous
//
#include <hip/hip_runtime.h>
#include <hip/hip_bf16.h>

typedef short bf16x8 __attribute__((ext_vector_type(8)));
typedef float f32x4 __attribute__((ext_vector_type(4)));
typedef unsigned short u16;

#define B 128
#define LQ 32
#define LK 128
#define D 128

// ws layout: l_bf16 (1 MiB) | r_bf16 (4 MiB) | sims (64 KiB)

static __device__ inline u16 f2bf_rne(float f) {
  union { float f; unsigned u; } v; v.f = f;
  unsigned r = v.u + 0x7fffu + ((v.u >> 16) & 1u);
  return (u16)(r >> 16);
}

// One wave per row (D=128 -> 2 floats/lane). Normalize + cast to bf16.
__global__ __launch_bounds__(256) void normalize_kernel(
    const float* __restrict__ left, const float* __restrict__ right,
    u16* __restrict__ l_out, u16* __restrict__ r_out) {
  int wave = (blockIdx.x * blockDim.x + threadIdx.x) >> 6;
  int lane = threadIdx.x & 63;
  const int n_l = B * LQ;
  const float* src; u16* dst; int row;
  if (wave < n_l) { src = left;  dst = l_out; row = wave; }
  else            { src = right; dst = r_out; row = wave - n_l; }
  float2 v = *reinterpret_cast<const float2*>(src + (size_t)row * D + lane * 2);
  float ss = v.x * v.x + v.y * v.y;
#pragma unroll
  for (int off = 1; off < 64; off <<= 1) ss += __shfl_xor(ss, off);
  float inv = 1.0f / fmaxf(sqrtf(ss), 1e-12f);
  unsigned packed = (unsigned)f2bf_rne(v.x * inv) |
                    ((unsigned)f2bf_rne(v.y * inv) << 16);
  *reinterpret_cast<unsigned*>(dst + (size_t)row * D + lane * 2) = packed;
}

// Pair-sims: per (x,y), T[j][i] = sum_k r[y][j][k] * l[x][i][k]  (M=j=128,
// N=i=32, K=128 via 16x16x32 bf16 MFMA). Then sim[x][y] = sum_i max_j T.
// Grid: 2048 blocks = 32 x-groups x 64 y-groups; 4 waves/block (wave = one x),
// 2 y per wave -> 8192 waves = ~8 waves/SIMD for latency hiding.
#define Y_PER_WAVE 2
__global__ __launch_bounds__(256) void maxsim_kernel(
    const u16* __restrict__ lb, const u16* __restrict__ rb,
    float* __restrict__ sims) {
  const int lane = threadIdx.x & 63;
  const int wv   = threadIdx.x >> 6;      // 0..3
  const int xg   = blockIdx.x >> 6;       // 0..31
  const int yg   = blockIdx.x & 63;       // 0..63
  const int x    = xg * 4 + wv;
  const int lo4  = lane & 15, hi2 = lane >> 4;
  const int frag_off = lo4 * D + hi2 * 8; // element offset within a 16-row tile

  // B operand (l[x]) fragments, fixed across y. B[k][i] = l[x][i][k].
  bf16x8 bfr[2][4];
#pragma unroll
  for (int ni = 0; ni < 2; ++ni)
#pragma unroll
    for (int k = 0; k < 4; ++k)
      bfr[ni][k] = *reinterpret_cast<const bf16x8*>(
          lb + (size_t)(x * LQ + ni * 16) * D + k * 32 + frag_off);

#pragma unroll
  for (int yy = 0; yy < Y_PER_WAVE; ++yy) {
    const int y = yg * Y_PER_WAVE + yy;
    const u16* rbase = rb + (size_t)y * LK * D;
    f32x4 acc[8][2];
#pragma unroll
    for (int mj = 0; mj < 8; ++mj)
#pragma unroll
      for (int ni = 0; ni < 2; ++ni)
        acc[mj][ni] = f32x4{0.f, 0.f, 0.f, 0.f};

#pragma unroll
    for (int mj = 0; mj < 8; ++mj) {
      bf16x8 afr[4];
#pragma unroll
      for (int k = 0; k < 4; ++k)
        afr[k] = *reinterpret_cast<const bf16x8*>(
            rbase + (size_t)mj * 16 * D + k * 32 + frag_off);
#pragma unroll
      for (int k = 0; k < 4; ++k)
#pragma unroll
        for (int ni = 0; ni < 2; ++ni)
          acc[mj][ni] = __builtin_amdgcn_mfma_f32_16x16x32_bf16(
              afr[k], bfr[ni][k], acc[mj][ni], 0, 0, 0);
    }

    // lane holds T[mj*16 + hi2*4 + r][ni*16 + lo4]
    float cmax0 = -3.0e38f, cmax1 = -3.0e38f;
#pragma unroll
    for (int mj = 0; mj < 8; ++mj)
#pragma unroll
      for (int r = 0; r < 4; ++r) {
        cmax0 = fmaxf(cmax0, acc[mj][0][r]);
        cmax1 = fmaxf(cmax1, acc[mj][1][r]);
      }
    cmax0 = fmaxf(cmax0, __shfl_xor(cmax0, 16));
    cmax0 = fmaxf(cmax0, __shfl_xor(cmax0, 32));
    cmax1 = fmaxf(cmax1, __shfl_xor(cmax1, 16));
    cmax1 = fmaxf(cmax1, __shfl_xor(cmax1, 32));
    float s = cmax0 + cmax1;
#pragma unroll
    for (int off = 1; off <= 8; off <<= 1) s += __shfl_xor(s, off);
    if (lane == 0) sims[x * B + y] = s;
  }
}

// log-softmax + CE. One block, 1024 threads = 16 waves; wave w does rows
// w*8..w*8+7, 64 lanes cover 128 cols (2 each) with shfl reductions.
__global__ __launch_bounds__(1024) void loss_kernel(
    const float* __restrict__ sims, const float* __restrict__ logit_scale,
    const int* __restrict__ pos_idx, float* __restrict__ out) {
  __shared__ float red[16];
  const int lane = threadIdx.x & 63;
  const int wv   = threadIdx.x >> 6;     // 0..15
  const float scale = expf(logit_scale[0]);
  float local = 0.f;
#pragma unroll
  for (int rr = 0; rr < 8; ++rr) {
    const int x = wv * 8 + rr;
    const float* row = sims + x * B;
    float a = row[lane], b2 = row[64 + lane];
    float m = fmaxf(a, b2);
#pragma unroll
    for (int off = 1; off < 64; off <<= 1) m = fmaxf(m, __shfl_xor(m, off));
    float ml = scale * m;
    float e = expf(scale * a - ml) + expf(scale * b2 - ml);
#pragma unroll
    for (int off = 1; off < 64; off <<= 1) e += __shfl_xor(e, off);
    int pos = pos_idx[x];
    float pv = __shfl(pos < 64 ? a : b2, pos & 63);  // row[pos]
    local += -(scale * pv - ml - logf(e));
  }
  if (lane == 0) red[wv] = local;
  __syncthreads();
  if (threadIdx.x == 0) {
    float t = 0.f;
#pragma unroll
    for (int i = 0; i < 16; ++i) t += red[i];
    out[0] = t / (float)B;
  }
}

extern "C" void kernel_launch(void* const* d_in, const int* in_sizes, int n_in,
                              void* d_out, int out_size, void* d_ws, size_t ws_size,
                              hipStream_t stream) {
  const float* left  = (const float*)d_in[0];
  const float* right = (const float*)d_in[1];
  const float* ls    = (const float*)d_in[2];
  const int*   pos   = (const int*)d_in[3];
  float* out = (float*)d_out;

  char* ws = (char*)d_ws;
  u16* lb   = (u16*)ws;
  u16* rbuf = (u16*)(ws + (size_t)B * LQ * D * 2);
  float* sims = (float*)(ws + (size_t)B * LQ * D * 2 + (size_t)B * LK * D * 2);

  int waves = B * LQ + B * LK;  // 20480 rows, 1 wave each
  normalize_kernel<<<waves / 4, 256, 0, stream>>>(left, right, lb, rbuf);
  maxsim_kernel<<<2048, 256, 0, stream>>>(lb, rbuf, sims);
  loss_kernel<<<1, 1024, 0, stream>>>(sims, ls, pos, out);
}

// Round 3
// 35.473 us; speedup vs baseline: 2.4673x; 2.3417x over previous
//
#include <hip/hip_runtime.h>
#include <hip/hip_bf16.h>

typedef short bf16x8 __attribute__((ext_vector_type(8)));
typedef float f32x4 __attribute__((ext_vector_type(4)));
typedef unsigned short u16;

#define B 128
#define LQ 32
#define LK 128
#define D 128
#define YPB 4
#define TILE_BYTES 32768  // one r[y] tile: 128*128*2B

// ws layout: l_bf16 (1 MiB) | r_bf16 (4 MiB) | sims (64 KiB)

static __device__ inline u16 f2bf_rne(float f) {
  union { float f; unsigned u; } v; v.f = f;
  unsigned r = v.u + 0x7fffu + ((v.u >> 16) & 1u);
  return (u16)(r >> 16);
}

__global__ __launch_bounds__(256) void normalize_kernel(
    const float* __restrict__ left, const float* __restrict__ right,
    u16* __restrict__ l_out, u16* __restrict__ r_out) {
  int wave = (blockIdx.x * blockDim.x + threadIdx.x) >> 6;
  int lane = threadIdx.x & 63;
  const int n_l = B * LQ;
  const float* src; u16* dst; int row;
  if (wave < n_l) { src = left;  dst = l_out; row = wave; }
  else            { src = right; dst = r_out; row = wave - n_l; }
  float2 v = *reinterpret_cast<const float2*>(src + (size_t)row * D + lane * 2);
  float ss = v.x * v.x + v.y * v.y;
#pragma unroll
  for (int off = 1; off < 64; off <<= 1) ss += __shfl_xor(ss, off);
  float inv = 1.0f / fmaxf(sqrtf(ss), 1e-12f);
  unsigned packed = (unsigned)f2bf_rne(v.x * inv) |
                    ((unsigned)f2bf_rne(v.y * inv) << 16);
  *reinterpret_cast<unsigned*>(dst + (size_t)row * D + lane * 2) = packed;
}

// Per (x,y): T[j][i] = sum_k r[y][j][k]*l[x][i][k]; sim = sum_i max_j T.
// Block: 4 waves x 2 x's = 8 x's, YPB y's, r[y] staged to LDS (dbuf, DMA,
// XOR-swizzled via pre-swizzled global source). Grid 16 xg * 32 yg = 512,
// 64KB LDS -> 2 blocks/CU, whole grid resident.
__global__ __launch_bounds__(256, 2) void maxsim_kernel(
    const u16* __restrict__ lb, const u16* __restrict__ rb,
    float* __restrict__ sims) {
  __shared__ char smem[2 * TILE_BYTES];
  const int tid  = threadIdx.x;
  const int lane = tid & 63;
  const int wv   = tid >> 6;          // 0..3
  const int xg   = blockIdx.x >> 5;   // 0..15
  const int yg   = blockIdx.x & 31;   // 0..31
  const int x0   = xg * 8 + wv * 2;
  const int lo4  = lane & 15, hi2 = lane >> 4;
  const int frag_off = lo4 * D + hi2 * 8;

  // ---- prologue: issue DMA for y0, then load l-fragments (bfr) ----
  {
    const char* ryb = (const char*)(rb + (size_t)(yg * YPB) * LK * D);
#pragma unroll
    for (int i = 0; i < 8; ++i) {
      unsigned Lrel = (unsigned)(i * 4096 + wv * 1024 + lane * 16);
      unsigned Goff = Lrel ^ (((Lrel >> 8) & 7) << 4);  // involution swizzle
      __builtin_amdgcn_global_load_lds(
          (const __attribute__((address_space(1))) void*)(ryb + Goff),
          (__attribute__((address_space(3))) void*)(smem + i * 4096 + wv * 1024),
          16, 0, 0);
    }
  }
  bf16x8 bfr[2][2][4];  // [xi][ni][k], B[k][i] = l[x][i][k]
  const u16* lxbase = lb + (size_t)x0 * LQ * D;
#pragma unroll
  for (int xi = 0; xi < 2; ++xi)
#pragma unroll
    for (int ni = 0; ni < 2; ++ni)
#pragma unroll
      for (int k = 0; k < 4; ++k)
        bfr[xi][ni][k] = *reinterpret_cast<const bf16x8*>(
            lxbase + (size_t)(xi * LQ + ni * 16) * D + k * 32 + frag_off);

  for (int yy = 0; yy < YPB; ++yy) {
    // issue next tile's DMA before waiting on current (counted vmcnt, T3/T4)
    if (yy + 1 < YPB) {
      const char* ryb = (const char*)(rb + (size_t)(yg * YPB + yy + 1) * LK * D);
      char* bufn = smem + ((yy + 1) & 1) * TILE_BYTES;
#pragma unroll
      for (int i = 0; i < 8; ++i) {
        unsigned Lrel = (unsigned)(i * 4096 + wv * 1024 + lane * 16);
        unsigned Goff = Lrel ^ (((Lrel >> 8) & 7) << 4);
        __builtin_amdgcn_global_load_lds(
            (const __attribute__((address_space(1))) void*)(ryb + Goff),
            (__attribute__((address_space(3))) void*)(bufn + i * 4096 + wv * 1024),
            16, 0, 0);
      }
      asm volatile("s_waitcnt vmcnt(8)" ::: "memory");  // current tile done
    } else {
      asm volatile("s_waitcnt vmcnt(0)" ::: "memory");
    }
    asm volatile("s_barrier" ::: "memory");

    const char* buf = smem + (yy & 1) * TILE_BYTES;
    float cmax[2][2];
#pragma unroll
    for (int xi = 0; xi < 2; ++xi)
#pragma unroll
      for (int ni = 0; ni < 2; ++ni) cmax[xi][ni] = -3.0e38f;

#pragma unroll 2
    for (int mj = 0; mj < 8; ++mj) {
      bf16x8 afr[4];
#pragma unroll
      for (int k = 0; k < 4; ++k) {
        unsigned Erel = (unsigned)((mj * 16 + lo4) * 256 + k * 64 + hi2 * 16);
        unsigned addr = Erel ^ (((Erel >> 8) & 7) << 4);
        afr[k] = *reinterpret_cast<const bf16x8*>(buf + addr);
      }
      f32x4 acc[2][2];
#pragma unroll
      for (int xi = 0; xi < 2; ++xi)
#pragma unroll
        for (int ni = 0; ni < 2; ++ni) acc[xi][ni] = f32x4{0.f, 0.f, 0.f, 0.f};
#pragma unroll
      for (int k = 0; k < 4; ++k)
#pragma unroll
        for (int xi = 0; xi < 2; ++xi)
#pragma unroll
          for (int ni = 0; ni < 2; ++ni)
            acc[xi][ni] = __builtin_amdgcn_mfma_f32_16x16x32_bf16(
                afr[k], bfr[xi][ni][k], acc[xi][ni], 0, 0, 0);
      // fold this mj's rows into running column-max (keeps acc live-range short)
#pragma unroll
      for (int xi = 0; xi < 2; ++xi)
#pragma unroll
        for (int ni = 0; ni < 2; ++ni)
#pragma unroll
          for (int r = 0; r < 4; ++r)
            cmax[xi][ni] = fmaxf(cmax[xi][ni], acc[xi][ni][r]);
    }
    asm volatile("s_barrier" ::: "memory");  // release buf for overwrite

    const int y = yg * YPB + yy;
#pragma unroll
    for (int xi = 0; xi < 2; ++xi) {
      float c0 = cmax[xi][0], c1 = cmax[xi][1];
      c0 = fmaxf(c0, __shfl_xor(c0, 16)); c0 = fmaxf(c0, __shfl_xor(c0, 32));
      c1 = fmaxf(c1, __shfl_xor(c1, 16)); c1 = fmaxf(c1, __shfl_xor(c1, 32));
      float s = c0 + c1;
#pragma unroll
      for (int off = 1; off <= 8; off <<= 1) s += __shfl_xor(s, off);
      if (lane == 0) sims[(x0 + xi) * B + y] = s;
    }
  }
}

// log-softmax + CE. 1 block, 1024 threads = 16 waves; wave w -> rows w*8..+7.
__global__ __launch_bounds__(1024) void loss_kernel(
    const float* __restrict__ sims, const float* __restrict__ logit_scale,
    const int* __restrict__ pos_idx, float* __restrict__ out) {
  __shared__ float red[16];
  const int lane = threadIdx.x & 63;
  const int wv   = threadIdx.x >> 6;
  const float scale = expf(logit_scale[0]);
  float local = 0.f;
#pragma unroll
  for (int rr = 0; rr < 8; ++rr) {
    const int x = wv * 8 + rr;
    const float* row = sims + x * B;
    float a = row[lane], b2 = row[64 + lane];
    float m = fmaxf(a, b2);
#pragma unroll
    for (int off = 1; off < 64; off <<= 1) m = fmaxf(m, __shfl_xor(m, off));
    float ml = scale * m;
    float e = expf(scale * a - ml) + expf(scale * b2 - ml);
#pragma unroll
    for (int off = 1; off < 64; off <<= 1) e += __shfl_xor(e, off);
    int pos = pos_idx[x];
    float pv = __shfl(pos < 64 ? a : b2, pos & 63);
    local += -(scale * pv - ml - logf(e));
  }
  if (lane == 0) red[wv] = local;
  __syncthreads();
  if (threadIdx.x == 0) {
    float t = 0.f;
#pragma unroll
    for (int i = 0; i < 16; ++i) t += red[i];
    out[0] = t / (float)B;
  }
}

extern "C" void kernel_launch(void* const* d_in, const int* in_sizes, int n_in,
                              void* d_out, int out_size, void* d_ws, size_t ws_size,
                              hipStream_t stream) {
  const float* left  = (const float*)d_in[0];
  const float* right = (const float*)d_in[1];
  const float* ls    = (const float*)d_in[2];
  const int*   pos   = (const int*)d_in[3];
  float* out = (float*)d_out;

  char* ws = (char*)d_ws;
  u16* lb   = (u16*)ws;
  u16* rbuf = (u16*)(ws + (size_t)B * LQ * D * 2);
  float* sims = (float*)(ws + (size_t)B * LQ * D * 2 + (size_t)B * LK * D * 2);

  int waves = B * LQ + B * LK;  // 20480 rows
  normalize_kernel<<<waves / 4, 256, 0, stream>>>(left, right, lb, rbuf);
  maxsim_kernel<<<512, 256, 0, stream>>>(lb, rbuf, sims);
  loss_kernel<<<1, 1024, 0, stream>>>(sims, ls, pos, out);
}

// Round 4
// 34.785 us; speedup vs baseline: 2.5162x; 1.0198x over previous
//
#include <hip/hip_runtime.h>
#include <hip/hip_bf16.h>

typedef short bf16x8 __attribute__((ext_vector_type(8)));
typedef float f32x16 __attribute__((ext_vector_type(16)));
typedef unsigned short u16;

#define B 128
#define LQ 32
#define LK 128
#define D 128
#define YPB 4
#define TILE_BYTES 32768  // one r[y] tile: 128 rows x 256 B

// ws layout: l_bf16 (1 MiB) | r_bf16 (4 MiB) | sims (64 KiB)

static __device__ inline u16 f2bf_rne(float f) {
  union { float f; unsigned u; } v; v.f = f;
  unsigned r = v.u + 0x7fffu + ((v.u >> 16) & 1u);
  return (u16)(r >> 16);
}

// XOR swizzle: spread each row's 16B slot using row&15 (rows at stride 256B
// would otherwise all hit banks 0-3). Involution; applied to BOTH the DMA
// global source and the LDS read address (rule #21).
static __device__ inline unsigned swz(unsigned a) {
  return a ^ (((a >> 8) & 15u) << 4);
}

__global__ __launch_bounds__(256) void normalize_kernel(
    const float* __restrict__ left, const float* __restrict__ right,
    u16* __restrict__ l_out, u16* __restrict__ r_out) {
  int wave = (blockIdx.x * blockDim.x + threadIdx.x) >> 6;
  int lane = threadIdx.x & 63;
  const int n_l = B * LQ;
  const float* src; u16* dst; int row;
  if (wave < n_l) { src = left;  dst = l_out; row = wave; }
  else            { src = right; dst = r_out; row = wave - n_l; }
  float2 v = *reinterpret_cast<const float2*>(src + (size_t)row * D + lane * 2);
  float ss = v.x * v.x + v.y * v.y;
#pragma unroll
  for (int off = 1; off < 64; off <<= 1) ss += __shfl_xor(ss, off);
  float inv = 1.0f / fmaxf(sqrtf(ss), 1e-12f);
  unsigned packed = (unsigned)f2bf_rne(v.x * inv) |
                    ((unsigned)f2bf_rne(v.y * inv) << 16);
  *reinterpret_cast<unsigned*>(dst + (size_t)row * D + lane * 2) = packed;
}

// Per (x,y): T[j][i] = sum_k r[y][j][k]*l[x][i][k] via 32x32x16 bf16 MFMA
// (M=j 128 -> 4 mj blocks, N=i=32=Lq in ONE block, K=128 -> 8 ks steps).
// sim[x][y] = sum_i max_j T. Block: 4 waves x 2 x = 8 x's, YPB y's; r[y]
// double-buffered in LDS via global_load_lds with pre-swizzled source.
// Grid 16 xg * 32 yg = 512 blocks, 64KB LDS -> 2 blocks/CU.
__global__ __launch_bounds__(256, 2) void maxsim_kernel(
    const u16* __restrict__ lb, const u16* __restrict__ rb,
    float* __restrict__ sims) {
  __shared__ char smem[2 * TILE_BYTES];
  const int tid  = threadIdx.x;
  const int lane = tid & 63;
  const int wv   = tid >> 6;          // 0..3
  const int xg   = blockIdx.x >> 5;   // 0..15
  const int yg   = blockIdx.x & 31;   // 0..31
  const int x0   = xg * 8 + wv * 2;
  const unsigned rr = lane & 31;      // A row / B col within 32-block
  const unsigned hh = (unsigned)lane >> 5;  // k-half select

  // ---- prologue: issue DMA for y0 immediately ----
  {
    const char* ryb = (const char*)(rb + (size_t)(yg * YPB) * LK * D);
#pragma unroll
    for (int i = 0; i < 8; ++i) {
      unsigned Lrel = (unsigned)(i * 4096 + wv * 1024 + lane * 16);
      __builtin_amdgcn_global_load_lds(
          (const __attribute__((address_space(1))) void*)(ryb + swz(Lrel)),
          (__attribute__((address_space(3))) void*)(smem + i * 4096 + wv * 1024),
          16, 0, 0);
    }
  }

  // Per-lane swizzled LDS read bases, one per ks (mj/buf go in offset imm).
  // afr element: row=rr (+32*mj), k = ks*16 + hh*8 + e  ->  physical byte
  // addr = rr*256 + (((ks*2)|hh)^(rr&15))*16 + mj*8192 (+bufsel*32768).
  unsigned kbase[8];
  const unsigned msk = rr & 15u;
#pragma unroll
  for (int ks = 0; ks < 8; ++ks)
    kbase[ks] = rr * 256u + (((((unsigned)ks << 1) | hh) ^ msk) << 4);

  // B operand fragments: bfr[xi][ks], lane holds col i=rr, k=hh*8+0..7.
  bf16x8 bfr[2][8];
#pragma unroll
  for (int xi = 0; xi < 2; ++xi) {
    const u16* lx = lb + (size_t)(x0 + xi) * LQ * D + (size_t)rr * D;
#pragma unroll
    for (int ks = 0; ks < 8; ++ks)
      bfr[xi][ks] = *reinterpret_cast<const bf16x8*>(lx + ks * 16 + hh * 8);
  }

  f32x16 z;
#pragma unroll
  for (int t = 0; t < 16; ++t) z[t] = 0.f;

#pragma unroll
  for (int yy = 0; yy < YPB; ++yy) {
    if (yy + 1 < YPB) {  // issue next tile, counted wait for current (T3/T4)
      const char* ryb = (const char*)(rb + (size_t)(yg * YPB + yy + 1) * LK * D);
      char* bufn = smem + ((yy + 1) & 1) * TILE_BYTES;
#pragma unroll
      for (int i = 0; i < 8; ++i) {
        unsigned Lrel = (unsigned)(i * 4096 + wv * 1024 + lane * 16);
        __builtin_amdgcn_global_load_lds(
            (const __attribute__((address_space(1))) void*)(ryb + swz(Lrel)),
            (__attribute__((address_space(3))) void*)(bufn + i * 4096 + wv * 1024),
            16, 0, 0);
      }
      asm volatile("s_waitcnt vmcnt(8)" ::: "memory");
    } else {
      asm volatile("s_waitcnt vmcnt(0)" ::: "memory");
    }
    asm volatile("s_barrier" ::: "memory");

    const char* buf = smem + (yy & 1) * TILE_BYTES;
    float cm0 = -3.0e38f, cm1 = -3.0e38f;

#pragma unroll
    for (int mj = 0; mj < 4; ++mj) {
      bf16x8 afr[8];
#pragma unroll
      for (int ks = 0; ks < 8; ++ks)
        afr[ks] = *reinterpret_cast<const bf16x8*>(buf + mj * 8192 + kbase[ks]);
      __builtin_amdgcn_s_setprio(1);
      f32x16 a0 = __builtin_amdgcn_mfma_f32_32x32x16_bf16(afr[0], bfr[0][0], z, 0, 0, 0);
      f32x16 a1 = __builtin_amdgcn_mfma_f32_32x32x16_bf16(afr[0], bfr[1][0], z, 0, 0, 0);
#pragma unroll
      for (int ks = 1; ks < 8; ++ks) {
        a0 = __builtin_amdgcn_mfma_f32_32x32x16_bf16(afr[ks], bfr[0][ks], a0, 0, 0, 0);
        a1 = __builtin_amdgcn_mfma_f32_32x32x16_bf16(afr[ks], bfr[1][ks], a1, 0, 0, 0);
      }
      __builtin_amdgcn_s_setprio(0);
      // fold 16 regs (all distinct j rows) into running scalar max, tree-wise
      float t0, t1;
#pragma unroll
      for (int t = 0; t < 16; t += 4) {
        t0 = fmaxf(fmaxf(a0[t], a0[t + 1]), fmaxf(a0[t + 2], a0[t + 3]));
        t1 = fmaxf(fmaxf(a1[t], a1[t + 1]), fmaxf(a1[t + 2], a1[t + 3]));
        cm0 = fmaxf(cm0, t0);
        cm1 = fmaxf(cm1, t1);
      }
    }
    asm volatile("s_barrier" ::: "memory");  // release buf for next DMA

    const int y = yg * YPB + yy;
    // lanes l and l+32 hold complementary row-sets -> xor32 completes max_j;
    // then lane holds colmax[i=lane&31]; butterfly over bits 0-4 sums 32 i's.
    cm0 = fmaxf(cm0, __shfl_xor(cm0, 32));
    cm1 = fmaxf(cm1, __shfl_xor(cm1, 32));
#pragma unroll
    for (int off = 1; off <= 16; off <<= 1) {
      cm0 += __shfl_xor(cm0, off);
      cm1 += __shfl_xor(cm1, off);
    }
    if (lane == 0) {
      sims[(x0 + 0) * B + y] = cm0;
      sims[(x0 + 1) * B + y] = cm1;
    }
  }
}

// log-softmax + CE. 1 block, 1024 threads = 16 waves; wave w -> rows w*8..+7.
__global__ __launch_bounds__(1024) void loss_kernel(
    const float* __restrict__ sims, const float* __restrict__ logit_scale,
    const int* __restrict__ pos_idx, float* __restrict__ out) {
  __shared__ float red[16];
  const int lane = threadIdx.x & 63;
  const int wv   = threadIdx.x >> 6;
  const float scale = expf(logit_scale[0]);
  float local = 0.f;
#pragma unroll
  for (int rr = 0; rr < 8; ++rr) {
    const int x = wv * 8 + rr;
    const float* row = sims + x * B;
    float a = row[lane], b2 = row[64 + lane];
    float m = fmaxf(a, b2);
#pragma unroll
    for (int off = 1; off < 64; off <<= 1) m = fmaxf(m, __shfl_xor(m, off));
    float ml = scale * m;
    float e = expf(scale * a - ml) + expf(scale * b2 - ml);
#pragma unroll
    for (int off = 1; off < 64; off <<= 1) e += __shfl_xor(e, off);
    int pos = pos_idx[x];
    float pv = __shfl(pos < 64 ? a : b2, pos & 63);
    local += -(scale * pv - ml - logf(e));
  }
  if (lane == 0) red[wv] = local;
  __syncthreads();
  if (threadIdx.x == 0) {
    float t = 0.f;
#pragma unroll
    for (int i = 0; i < 16; ++i) t += red[i];
    out[0] = t / (float)B;
  }
}

extern "C" void kernel_launch(void* const* d_in, const int* in_sizes, int n_in,
                              void* d_out, int out_size, void* d_ws, size_t ws_size,
                              hipStream_t stream) {
  const float* left  = (const float*)d_in[0];
  const float* right = (const float*)d_in[1];
  const float* ls    = (const float*)d_in[2];
  const int*   pos   = (const int*)d_in[3];
  float* out = (float*)d_out;

  char* ws = (char*)d_ws;
  u16* lb   = (u16*)ws;
  u16* rbuf = (u16*)(ws + (size_t)B * LQ * D * 2);
  float* sims = (float*)(ws + (size_t)B * LQ * D * 2 + (size_t)B * LK * D * 2);

  int waves = B * LQ + B * LK;  // 20480 rows
  normalize_kernel<<<waves / 4, 256, 0, stream>>>(left, right, lb, rbuf);
  maxsim_kernel<<<512, 256, 0, stream>>>(lb, rbuf, sims);
  loss_kernel<<<1, 1024, 0, stream>>>(sims, ls, pos, out);
}